// Round 1
// baseline (1158.383 us; speedup 1.0000x reference)
//
#include <hip/hip_runtime.h>
#include <math.h>

// ---------------- problem constants ----------------
constexpr int HD = 48, WD = 48, LQ = HD * WD;     // 2304 downsampled positions / patches
constexpr int CC = 64;                             // channels
constexpr int HH = 96, WW = 96, NPIX = HH * WW;    // 9216 full-res pixels
constexpr int KC = CC * 9;                         // 576 im2col K
constexpr int ND = 16 * CC;                        // 1024 deconv GEMM N
constexpr long LL = (long)LQ * LQ;                 // 5,308,416

static __device__ __forceinline__ float eluf(float x) {
  return x > 0.f ? x : expm1f(x);
}

// ---------------- pack downsampled f/b as [q][c] ----------------
__global__ void pack_fdbd(const float* __restrict__ f, const float* __restrict__ bimg,
                          float* __restrict__ fdt, float* __restrict__ bdt, int batchBase) {
  int b = batchBase + blockIdx.z;
  int idx = blockIdx.x * 256 + threadIdx.x;      // < CC*LQ = 147456
  int c = idx / LQ, r = idx % LQ;
  int y = r / WD, x = r % WD;
  long src = ((long)(b * CC + c) * HH + 2 * y) * WW + 2 * x;
  long dst = (long)b * LQ * CC + (long)r * CC + c;
  fdt[dst] = f[src];
  bdt[dst] = bimg[src];
}

// ---------------- per-position squared-channel sums ----------------
__global__ void sq_kernel(const float* __restrict__ bdt, float* __restrict__ sq, int batchBase) {
  int b = batchBase + blockIdx.z;
  int q = blockIdx.x;
  int c = threadIdx.x;                            // 64 = one wave
  float v = bdt[(long)b * LQ * CC + (long)q * CC + c];
  v *= v;
  for (int off = 32; off; off >>= 1) v += __shfl_down(v, off);
  if (c == 0) sq[b * LQ + q] = v;
}

// ---------------- inv patch norms + valid-mask mm ----------------
__global__ void prep_l(const float* __restrict__ sq, const float* __restrict__ mask,
                       float* __restrict__ invn, float* __restrict__ mmb, int batchBase) {
  int b = batchBase + blockIdx.z;
  int l = blockIdx.x * 256 + threadIdx.x;        // < LQ exactly (grid 9)
  int li = l / WD, lj = l % WD;
  float ss = 0.f, mv = 0.f;
  for (int du = -1; du <= 1; ++du)
    for (int dv = -1; dv <= 1; ++dv) {
      int yy = li + du, xx = lj + dv;
      if ((unsigned)yy < (unsigned)HD && (unsigned)xx < (unsigned)WD) {
        ss += sq[b * LQ + yy * WD + xx];
        mv += mask[b * LQ + yy * WD + xx];
      }
    }
  invn[b * LQ + l] = 1.f / fmaxf(sqrtf(ss), 1e-4f);
  mmb[b * LQ + l] = (mv == 0.f) ? 1.f : 0.f;
}

// ---------------- generic fp32 GEMM: C = A * B^T ----------------
// A: M x K row-major, B: N x K row-major, C: M x N row-major. All dims divide tiles.
// EPI 0: plain store. EPI 1: bias+ELU, store row-major (HWC when N=64).
// EPI 2: bias+ELU, store NCHW to d_out (decode m -> (b,y,x)).
template <int BM, int BN, int EPI>
__global__ __launch_bounds__(256) void gemm_abt(
    const float* __restrict__ A, const float* __restrict__ B, float* __restrict__ C,
    int M, int N, int K, long sA, long sB, long sC,
    const float* __restrict__ bias, int batchBase) {
  constexpr int TM = 8, TN = 8, BK = 16;
  constexpr int LDA = BM + 4, LDB = BN + 4;
  __shared__ float As[BK][LDA];
  __shared__ float Bs[BK][LDB];
  const int z = blockIdx.z;
  A += (long)z * sA;
  B += (long)z * sB;
  const int tn0 = blockIdx.x * BN;
  const int tm0 = blockIdx.y * BM;
  const int tid = threadIdx.x;
  constexpr int TXN = BN / TN;
  const int tx = tid % TXN;
  const int ty = tid / TXN;
  float acc[TM][TN];
#pragma unroll
  for (int m = 0; m < TM; ++m)
#pragma unroll
    for (int n = 0; n < TN; ++n) acc[m][n] = 0.f;

  constexpr int A4 = BM * BK / 4 / 256;
  constexpr int B4 = BN * BK / 4 / 256;
  for (int k0 = 0; k0 < K; k0 += BK) {
#pragma unroll
    for (int s = 0; s < A4; ++s) {
      int idx = tid + s * 256;
      int row = idx >> 2;
      int k4 = idx & 3;
      float4 v = *(const float4*)(A + (long)(tm0 + row) * K + (k0 + k4 * 4));
      As[k4 * 4 + 0][row] = v.x;
      As[k4 * 4 + 1][row] = v.y;
      As[k4 * 4 + 2][row] = v.z;
      As[k4 * 4 + 3][row] = v.w;
    }
#pragma unroll
    for (int s = 0; s < B4; ++s) {
      int idx = tid + s * 256;
      int row = idx >> 2;
      int k4 = idx & 3;
      float4 v = *(const float4*)(B + (long)(tn0 + row) * K + (k0 + k4 * 4));
      Bs[k4 * 4 + 0][row] = v.x;
      Bs[k4 * 4 + 1][row] = v.y;
      Bs[k4 * 4 + 2][row] = v.z;
      Bs[k4 * 4 + 3][row] = v.w;
    }
    __syncthreads();
#pragma unroll
    for (int kk = 0; kk < BK; ++kk) {
      float a[TM], b[TN];
      *(float4*)&a[0] = *(const float4*)&As[kk][ty * TM];
      *(float4*)&a[4] = *(const float4*)&As[kk][ty * TM + 4];
      *(float4*)&b[0] = *(const float4*)&Bs[kk][tx * TN];
      *(float4*)&b[4] = *(const float4*)&Bs[kk][tx * TN + 4];
#pragma unroll
      for (int m = 0; m < TM; ++m)
#pragma unroll
        for (int n = 0; n < TN; ++n) acc[m][n] = fmaf(a[m], b[n], acc[m][n]);
    }
    __syncthreads();
  }

  if (EPI == 0) {
    C += (long)z * sC;
#pragma unroll
    for (int m = 0; m < TM; ++m) {
      long row = tm0 + ty * TM + m;
      float4 v0 = make_float4(acc[m][0], acc[m][1], acc[m][2], acc[m][3]);
      float4 v1 = make_float4(acc[m][4], acc[m][5], acc[m][6], acc[m][7]);
      *(float4*)(C + row * N + tn0 + tx * TN) = v0;
      *(float4*)(C + row * N + tn0 + tx * TN + 4) = v1;
    }
  } else if (EPI == 1) {
#pragma unroll
    for (int m = 0; m < TM; ++m) {
      long row = tm0 + ty * TM + m;
      float o[TN];
#pragma unroll
      for (int n = 0; n < TN; ++n) {
        int oc = tn0 + tx * TN + n;
        o[n] = eluf(acc[m][n] + bias[oc]);
      }
      *(float4*)(C + row * N + tn0 + tx * TN) = make_float4(o[0], o[1], o[2], o[3]);
      *(float4*)(C + row * N + tn0 + tx * TN + 4) = make_float4(o[4], o[5], o[6], o[7]);
    }
  } else {  // EPI == 2: NCHW output with bias+ELU
#pragma unroll
    for (int m = 0; m < TM; ++m) {
      long row = tm0 + ty * TM + m;
      int bl = batchBase + (int)(row / NPIX);
      int r = (int)(row % NPIX);
      int yy = r / WW, xx = r % WW;
#pragma unroll
      for (int n = 0; n < TN; ++n) {
        int oc = tn0 + tx * TN + n;
        float v = eluf(acc[m][n] + bias[oc]);
        C[(((long)bl * CC + oc) * HH + yy) * WW + xx] = v;
      }
    }
  }
}

// ---------------- 3-tap diagonal stencils ----------------
// MODE 0: patch v-sum (+-1, gated per-axis on j/lj)
// MODE 1: patch u-sum (+-48, gated per-axis on i/li), then * inv_norm[col]
// MODE 2: fuse_conv #1 (flat +-1 diagonal, gated on flat range)
template <int MODE>
__global__ void stencil3(const float* __restrict__ in, float* __restrict__ out,
                         long sBuf, const float* __restrict__ scale, int batchBase) {
  int z = blockIdx.z;
  const float* I = in + (long)z * sBuf;
  float* O = out + (long)z * sBuf;
  int idx = blockIdx.x * 256 + threadIdx.x;      // < LQ*LQ (fits int)
  int p = idx / LQ, q = idx - p * LQ;
  float s = I[idx];
  if (MODE == 0) {
    int j = p % WD, lj = q % WD;
    if (j > 0 && lj > 0) s += I[idx - (LQ + 1)];
    if (j < WD - 1 && lj < WD - 1) s += I[idx + (LQ + 1)];
  } else if (MODE == 1) {
    int i = p / WD, li = q / WD;
    if (i > 0 && li > 0) s += I[idx - WD * (LQ + 1)];
    if (i < HD - 1 && li < HD - 1) s += I[idx + WD * (LQ + 1)];
    s *= scale[(long)(batchBase + z) * LQ + q];
  } else {
    if (p > 0 && q > 0) s += I[idx - (LQ + 1)];
    if (p < LQ - 1 && q < LQ - 1) s += I[idx + (LQ + 1)];
  }
  O[idx] = s;
}

// ---------------- fuse_conv #2 in transposed index space, write back untransposed ----------------
__global__ void fuse2_reindex(const float* __restrict__ F1b, float* __restrict__ SF, long sBuf) {
  int z = blockIdx.z;
  const float* I = F1b + (long)z * sBuf;
  float* O = SF + (long)z * sBuf;
  int idx = blockIdx.x * 256 + threadIdx.x;
  int p = idx / LQ, l = idx - p * LQ;
  int i = p / WD, j = p % WD;
  int li = l / WD, lj = l % WD;
  int pp = j * HD + i, ll = lj * HD + li;        // transposed flat indices
  float s = 0.f;
#pragma unroll
  for (int d = -1; d <= 1; ++d) {
    int a = pp + d, bb = ll + d;
    if ((unsigned)a < (unsigned)LQ && (unsigned)bb < (unsigned)LQ) {
      int r = (a % HD) * WD + (a / HD);          // decode back to original layout
      int c = (bb % HD) * WD + (bb / HD);
      s += I[(long)r * LQ + c];
    }
  }
  O[idx] = s;
}

// ---------------- masked softmax over l per row p, + argmax -> off ----------------
__global__ __launch_bounds__(256) void softmax_row(float* __restrict__ S, long sBuf,
                                                   const float* __restrict__ mmb,
                                                   float* __restrict__ offout, int batchBase) {
  int z = blockIdx.z;
  int b = batchBase + z;
  int p = blockIdx.x;
  float* row = S + (long)z * sBuf + (long)p * LQ;
  const float* mmr = mmb + (long)b * LQ;
  int tid = threadIdx.x;
  __shared__ float rbuf[256];
  __shared__ int ibuf[256];
  float zv[9], mloc[9];
  float mx = -1e30f;
#pragma unroll
  for (int it = 0; it < 9; ++it) {
    int l = it * 256 + tid;
    float m_ = mmr[l];
    float v = (m_ != 0.f) ? row[l] * 10.f : 0.f;
    zv[it] = v;
    mloc[it] = m_;
    mx = fmaxf(mx, v);
  }
  rbuf[tid] = mx;
  __syncthreads();
  for (int s = 128; s; s >>= 1) {
    if (tid < s) rbuf[tid] = fmaxf(rbuf[tid], rbuf[tid + s]);
    __syncthreads();
  }
  float M = rbuf[0];
  __syncthreads();
  float ev[9];
  float sum = 0.f;
#pragma unroll
  for (int it = 0; it < 9; ++it) {
    ev[it] = expf(zv[it] - M);
    sum += ev[it];
  }
  rbuf[tid] = sum;
  __syncthreads();
  for (int s = 128; s; s >>= 1) {
    if (tid < s) rbuf[tid] += rbuf[tid + s];
    __syncthreads();
  }
  float inv = 1.f / rbuf[0];
  __syncthreads();
  float bv = -1.f;
  int bi = 0;
#pragma unroll
  for (int it = 0; it < 9; ++it) {
    int l = it * 256 + tid;
    float post = (mloc[it] != 0.f) ? ev[it] * inv : 0.f;
    row[l] = post;
    if (post > bv) { bv = post; bi = l; }       // within-thread l increasing -> first-max kept
  }
  rbuf[tid] = bv;
  ibuf[tid] = bi;
  __syncthreads();
  for (int s = 128; s; s >>= 1) {
    if (tid < s) {
      float ov = rbuf[tid + s];
      int oi = ibuf[tid + s];
      if (ov > rbuf[tid] || (ov == rbuf[tid] && oi < ibuf[tid])) {
        rbuf[tid] = ov;
        ibuf[tid] = oi;
      }
    }
    __syncthreads();
  }
  if (tid == 0) {
    int best = ibuf[0];
    int i = p / WD, j = p % WD;
    offout[((long)b * 2 + 0) * LQ + p] = (float)(best / WD - i);
    offout[((long)b * 2 + 1) * LQ + p] = (float)(best % WD - j);
  }
}

// ---------------- pack deconv weights WdT[(ku*4+kv)*64+o][l] ----------------
__global__ void pack_wd(const float* __restrict__ bimg, float* __restrict__ WdT,
                        long sWd, int batchBase) {
  int z = blockIdx.z;
  int b = batchBase + z;
  int idx = blockIdx.x * 256 + threadIdx.x;      // < ND*LQ
  int n = idx / LQ, l = idx - n * LQ;
  int o = n % CC, kuv = n / CC, ku = kuv >> 2, kv = kuv & 3;
  int li = l / WD, lj = l % WD;
  int yy = 2 * li + ku - 1, xx = 2 * lj + kv - 1;
  float v = 0.f;
  if ((unsigned)yy < (unsigned)HH && (unsigned)xx < (unsigned)WW)
    v = bimg[((long)(b * CC + o) * HH + yy) * WW + xx];
  WdT[(long)z * sWd + idx] = v;
}

// ---------------- scatter deconv GEMM result into HWC y_pre (incl. /4) ----------------
__global__ void scatter_deconv(const float* __restrict__ Mo, long sMo,
                               float* __restrict__ ypre, int batchBase) {
  int z = blockIdx.z;
  int b = batchBase + z;
  int o = threadIdx.x & 63, xq = threadIdx.x >> 6;
  int X = blockIdx.x * 4 + xq, Y = blockIdx.y;
  const float* M = Mo + (long)z * sMo;
  int iA, kuA, iB, kuB;
  if (Y & 1) { iA = (Y + 1) >> 1; kuA = 0; iB = (Y - 1) >> 1; kuB = 2; }
  else       { iA = Y >> 1;       kuA = 1; iB = (Y >> 1) - 1; kuB = 3; }
  int jA, kvA, jB, kvB;
  if (X & 1) { jA = (X + 1) >> 1; kvA = 0; jB = (X - 1) >> 1; kvB = 2; }
  else       { jA = X >> 1;       kvA = 1; jB = (X >> 1) - 1; kvB = 3; }
  int is[2] = {iA, iB}, kus[2] = {kuA, kuB};
  int js[2] = {jA, jB}, kvs[2] = {kvA, kvB};
  float s = 0.f;
#pragma unroll
  for (int a = 0; a < 2; ++a) {
    if ((unsigned)is[a] >= (unsigned)HD) continue;
#pragma unroll
    for (int c = 0; c < 2; ++c) {
      if ((unsigned)js[c] >= (unsigned)WD) continue;
      s += M[(long)(is[a] * WD + js[c]) * ND + (kus[a] * 4 + kvs[c]) * CC + o];
    }
  }
  ypre[((long)b * NPIX + Y * WW + X) * CC + o] = 0.25f * s;
}

// ---------------- pack conv weights as [oc][(u*3+v)*64+c] ----------------
__global__ void pack_w(const float* __restrict__ w1, const float* __restrict__ w2,
                       float* __restrict__ w1t, float* __restrict__ w2t) {
  int idx = blockIdx.x * 256 + threadIdx.x;      // < 2*CC*KC
  int sel = idx / (CC * KC);
  int r = idx % (CC * KC);
  int oc = r / KC, k = r % KC;
  int uv = k / CC, c = k % CC;
  const float* src = sel ? w2 : w1;
  float v = src[(long)(oc * CC + c) * 9 + uv];
  (sel ? w2t : w1t)[r] = v;
}

// ---------------- im2col from HWC source (3x3, pad 1), K order (u,v,c) ----------------
__global__ void im2col3(const float* __restrict__ src, float* __restrict__ Acol) {
  int t = blockIdx.x * 256 + threadIdx.x;        // one float4 per thread
  int m = t / 144, k4 = t % 144;
  int uv = k4 >> 4, c4 = k4 & 15;
  int u = uv / 3, v = uv % 3;
  int bl = m / NPIX, r = m % NPIX;
  int y = r / WW, x = r % WW;
  int yy = y + u - 1, xx = x + v - 1;
  float4 val = make_float4(0.f, 0.f, 0.f, 0.f);
  if ((unsigned)yy < (unsigned)HH && (unsigned)xx < (unsigned)WW)
    val = *(const float4*)(src + ((long)bl * NPIX + yy * WW + xx) * CC + c4 * 4);
  *(float4*)(Acol + (long)m * KC + k4 * 4) = val;
}

// ---------------- host ----------------
extern "C" void kernel_launch(void* const* d_in, const int* in_sizes, int n_in,
                              void* d_out, int out_size, void* d_ws, size_t ws_size,
                              hipStream_t stream) {
  const float* f = (const float*)d_in[0];
  const float* bimg = (const float*)d_in[1];
  const float* mask = (const float*)d_in[2];
  const float* w1 = (const float*)d_in[3];
  const float* b1 = (const float*)d_in[4];
  const float* w2 = (const float*)d_in[5];
  const float* b2 = (const float*)d_in[6];
  float* out = (float*)d_out;
  float* offout = out + 4L * CC * NPIX;          // off region (written as float)

  char* w = (char*)d_ws;
  float* fdt = (float*)w;  w += 4L * LQ * CC * 4;
  float* bdt = (float*)w;  w += 4L * LQ * CC * 4;
  float* sqb = (float*)w;  w += 4L * LQ * 4;
  float* invn = (float*)w; w += 4L * LQ * 4;
  float* mmb = (float*)w;  w += 4L * LQ * 4;
  float* w1t = (float*)w;  w += (long)CC * KC * 4;
  float* w2t = (float*)w;  w += (long)CC * KC * 4;
  float* ypre = (float*)w; w += 4L * NPIX * CC * 4;

  size_t fixed = (size_t)(w - (char*)d_ws);
  size_t szS_full = (size_t)4 * LL * 4;
  size_t szS_seq = (size_t)LL * 4;
  size_t szM_full = (size_t)4 * LQ * ND * 4;
  size_t szM_seq = (size_t)LQ * ND * 4;
  size_t need_full = fixed + szM_full + 2 * szS_full;
  bool full = (ws_size >= need_full);

  float* RM = (float*)w;
  float* R2 = (float*)(w + (full ? szM_full : szM_seq));
  float* R3 = (float*)(w + (full ? szM_full + szS_full : szM_seq + szS_seq));

  long sS = full ? LL : 0;
  long sM = full ? (long)LQ * ND : 0;
  long sWd = full ? (long)ND * LQ : 0;
  long sFD = (long)LQ * CC;
  int NB = full ? 4 : 1;
  int nIter = full ? 1 : 4;

  pack_w<<<dim3(288), 256, 0, stream>>>(w1, w2, w1t, w2t);

  for (int itb = 0; itb < nIter; ++itb) {
    int bb = full ? 0 : itb;
    pack_fdbd<<<dim3(576, 1, NB), 256, 0, stream>>>(f, bimg, fdt, bdt, bb);
    sq_kernel<<<dim3(LQ, 1, NB), 64, 0, stream>>>(bdt, sqb, bb);
    prep_l<<<dim3(9, 1, NB), 256, 0, stream>>>(sqb, mask, invn, mmb, bb);
    // Gram matrix G = fdt * bdt^T  (K = 64)
    gemm_abt<128, 128, 0><<<dim3(LQ / 128, LQ / 128, NB), 256, 0, stream>>>(
        fdt + (long)bb * sFD, bdt + (long)bb * sFD, R2, LQ, LQ, CC, sFD, sFD, sS,
        nullptr, 0);
    // patch box-sum (v then u, u-pass applies inv_norm) then fuse passes
    stencil3<0><<<dim3(20736, 1, NB), 256, 0, stream>>>(R2, R3, sS, nullptr, bb);
    stencil3<1><<<dim3(20736, 1, NB), 256, 0, stream>>>(R3, R2, sS, invn, bb);
    stencil3<2><<<dim3(20736, 1, NB), 256, 0, stream>>>(R2, R3, sS, nullptr, bb);
    fuse2_reindex<<<dim3(20736, 1, NB), 256, 0, stream>>>(R3, R2, sS);
    softmax_row<<<dim3(LQ, 1, NB), 256, 0, stream>>>(R2, sS, mmb, offout, bb);
    // deconv as GEMM: post (2304x2304) @ WdT^T (1024x2304)
    pack_wd<<<dim3(9216, 1, NB), 256, 0, stream>>>(bimg, R3, sWd, bb);
    gemm_abt<128, 128, 0><<<dim3(ND / 128, LQ / 128, NB), 256, 0, stream>>>(
        R2, R3, RM, LQ, ND, LQ, sS, sWd, sM, nullptr, 0);
    scatter_deconv<<<dim3(24, 96, NB), 256, 0, stream>>>(RM, sM, ypre, bb);

    if (full) {
      im2col3<<<dim3(20736), 256, 0, stream>>>(ypre, R2);
      gemm_abt<256, 64, 1><<<dim3(1, 4 * NPIX / 256, 1), 256, 0, stream>>>(
          R2, w1t, R3, 4 * NPIX, CC, KC, 0, 0, 0, b1, 0);
      im2col3<<<dim3(20736), 256, 0, stream>>>(R3, R2);
      gemm_abt<256, 64, 2><<<dim3(1, 4 * NPIX / 256, 1), 256, 0, stream>>>(
          R2, w2t, out, 4 * NPIX, CC, KC, 0, 0, 0, b2, 0);
    } else {
      im2col3<<<dim3(5184), 256, 0, stream>>>(ypre + (long)bb * NPIX * CC, R2);
      gemm_abt<256, 64, 1><<<dim3(1, NPIX / 256, 1), 256, 0, stream>>>(
          R2, w1t, R3, NPIX, CC, KC, 0, 0, 0, b1, 0);
      im2col3<<<dim3(5184), 256, 0, stream>>>(R3, R2);
      gemm_abt<256, 64, 2><<<dim3(1, NPIX / 256, 1), 256, 0, stream>>>(
          R2, w2t, out, NPIX, CC, KC, 0, 0, 0, b2, bb);
    }
  }
}

// Round 2
// 670.399 us; speedup vs baseline: 1.7279x; 1.7279x over previous
//
#include <hip/hip_runtime.h>
#include <math.h>

// ---------------- problem constants ----------------
constexpr int HD = 48, WD = 48, LQ = HD * WD;     // 2304 downsampled positions / patches
constexpr int CC = 64;                             // channels
constexpr int HH = 96, WW = 96, NPIX = HH * WW;    // 9216 full-res pixels
constexpr int KC = CC * 9;                         // 576 im2col K
constexpr int ND = 16 * CC;                        // 1024 deconv GEMM N
constexpr long LL = (long)LQ * LQ;                 // 5,308,416

typedef __attribute__((ext_vector_type(8))) short bf16x8;
typedef __attribute__((ext_vector_type(4))) float f32x4;

static __device__ __forceinline__ float eluf(float x) {
  return x > 0.f ? x : expm1f(x);
}
static __device__ __forceinline__ unsigned short f2bf(float x) {
  unsigned u = __float_as_uint(x);
  unsigned r = (u + 0x7fffu + ((u >> 16) & 1u)) >> 16;
  return (unsigned short)r;
}

// ---------------- pack downsampled f/b as [q][c] ----------------
__global__ void pack_fdbd(const float* __restrict__ f, const float* __restrict__ bimg,
                          float* __restrict__ fdt, float* __restrict__ bdt, int batchBase) {
  int b = batchBase + blockIdx.z;
  int idx = blockIdx.x * 256 + threadIdx.x;      // < CC*LQ = 147456
  int c = idx / LQ, r = idx % LQ;
  int y = r / WD, x = r % WD;
  long src = ((long)(b * CC + c) * HH + 2 * y) * WW + 2 * x;
  long dst = (long)b * LQ * CC + (long)r * CC + c;
  fdt[dst] = f[src];
  bdt[dst] = bimg[src];
}

// ---------------- per-position squared-channel sums ----------------
__global__ void sq_kernel(const float* __restrict__ bdt, float* __restrict__ sq, int batchBase) {
  int b = batchBase + blockIdx.z;
  int q = blockIdx.x;
  int c = threadIdx.x;                            // 64 = one wave
  float v = bdt[(long)b * LQ * CC + (long)q * CC + c];
  v *= v;
  for (int off = 32; off; off >>= 1) v += __shfl_down(v, off);
  if (c == 0) sq[b * LQ + q] = v;
}

// ---------------- inv patch norms + valid-mask mm ----------------
__global__ void prep_l(const float* __restrict__ sq, const float* __restrict__ mask,
                       float* __restrict__ invn, float* __restrict__ mmb, int batchBase) {
  int b = batchBase + blockIdx.z;
  int l = blockIdx.x * 256 + threadIdx.x;        // < LQ exactly (grid 9)
  int li = l / WD, lj = l % WD;
  float ss = 0.f, mv = 0.f;
  for (int du = -1; du <= 1; ++du)
    for (int dv = -1; dv <= 1; ++dv) {
      int yy = li + du, xx = lj + dv;
      if ((unsigned)yy < (unsigned)HD && (unsigned)xx < (unsigned)WD) {
        ss += sq[b * LQ + yy * WD + xx];
        mv += mask[b * LQ + yy * WD + xx];
      }
    }
  invn[b * LQ + l] = 1.f / fmaxf(sqrtf(ss), 1e-4f);
  mmb[b * LQ + l] = (mv == 0.f) ? 1.f : 0.f;
}

// ---------------- generic fp32 GEMM: C = A * B^T ----------------
// A: M x K row-major, B: N x K row-major, C: M x N row-major. All dims divide tiles.
// EPI 0: plain store. EPI 1: bias+ELU, row-major. EPI 2: bias+ELU, NCHW to d_out.
template <int BM, int BN, int EPI, int TM>
__global__ __launch_bounds__(256) void gemm_abt(
    const float* __restrict__ A, const float* __restrict__ B, float* __restrict__ C,
    int M, int N, int K, long sA, long sB, long sC,
    const float* __restrict__ bias, int batchBase) {
  constexpr int TN = 8, BK = 16;
  constexpr int LDA = BM + 4, LDB = BN + 4;
  __shared__ float As[BK][LDA];
  __shared__ float Bs[BK][LDB];
  const int z = blockIdx.z;
  A += (long)z * sA;
  B += (long)z * sB;
  const int tn0 = blockIdx.x * BN;
  const int tm0 = blockIdx.y * BM;
  const int tid = threadIdx.x;
  constexpr int TXN = BN / TN;
  const int tx = tid % TXN;
  const int ty = tid / TXN;
  float acc[TM][TN];
#pragma unroll
  for (int m = 0; m < TM; ++m)
#pragma unroll
    for (int n = 0; n < TN; ++n) acc[m][n] = 0.f;

  constexpr int A4 = BM * BK / 4 / 256;
  constexpr int B4 = BN * BK / 4 / 256;
  for (int k0 = 0; k0 < K; k0 += BK) {
#pragma unroll
    for (int s = 0; s < A4; ++s) {
      int idx = tid + s * 256;
      int row = idx >> 2;
      int k4 = idx & 3;
      float4 v = *(const float4*)(A + (long)(tm0 + row) * K + (k0 + k4 * 4));
      As[k4 * 4 + 0][row] = v.x;
      As[k4 * 4 + 1][row] = v.y;
      As[k4 * 4 + 2][row] = v.z;
      As[k4 * 4 + 3][row] = v.w;
    }
#pragma unroll
    for (int s = 0; s < B4; ++s) {
      int idx = tid + s * 256;
      int row = idx >> 2;
      int k4 = idx & 3;
      float4 v = *(const float4*)(B + (long)(tn0 + row) * K + (k0 + k4 * 4));
      Bs[k4 * 4 + 0][row] = v.x;
      Bs[k4 * 4 + 1][row] = v.y;
      Bs[k4 * 4 + 2][row] = v.z;
      Bs[k4 * 4 + 3][row] = v.w;
    }
    __syncthreads();
#pragma unroll
    for (int kk = 0; kk < BK; ++kk) {
      float a[TM], b[TN];
#pragma unroll
      for (int m4 = 0; m4 < TM; m4 += 4)
        *(float4*)&a[m4] = *(const float4*)&As[kk][ty * TM + m4];
#pragma unroll
      for (int n4 = 0; n4 < TN; n4 += 4)
        *(float4*)&b[n4] = *(const float4*)&Bs[kk][tx * TN + n4];
#pragma unroll
      for (int m = 0; m < TM; ++m)
#pragma unroll
        for (int n = 0; n < TN; ++n) acc[m][n] = fmaf(a[m], b[n], acc[m][n]);
    }
    __syncthreads();
  }

  if (EPI == 0) {
    C += (long)z * sC;
#pragma unroll
    for (int m = 0; m < TM; ++m) {
      long row = tm0 + ty * TM + m;
      *(float4*)(C + row * N + tn0 + tx * TN) =
          make_float4(acc[m][0], acc[m][1], acc[m][2], acc[m][3]);
      *(float4*)(C + row * N + tn0 + tx * TN + 4) =
          make_float4(acc[m][4], acc[m][5], acc[m][6], acc[m][7]);
    }
  } else if (EPI == 1) {
#pragma unroll
    for (int m = 0; m < TM; ++m) {
      long row = tm0 + ty * TM + m;
      float o[TN];
#pragma unroll
      for (int n = 0; n < TN; ++n) {
        int oc = tn0 + tx * TN + n;
        o[n] = eluf(acc[m][n] + bias[oc]);
      }
      *(float4*)(C + row * N + tn0 + tx * TN) = make_float4(o[0], o[1], o[2], o[3]);
      *(float4*)(C + row * N + tn0 + tx * TN + 4) = make_float4(o[4], o[5], o[6], o[7]);
    }
  } else {  // EPI == 2: NCHW output with bias+ELU
#pragma unroll
    for (int m = 0; m < TM; ++m) {
      long row = tm0 + ty * TM + m;
      int bl = batchBase + (int)(row / NPIX);
      int r = (int)(row % NPIX);
      int yy = r / WW, xx = r % WW;
#pragma unroll
      for (int n = 0; n < TN; ++n) {
        int oc = tn0 + tx * TN + n;
        float v = eluf(acc[m][n] + bias[oc]);
        C[(((long)bl * CC + oc) * HH + yy) * WW + xx] = v;
      }
    }
  }
}

// ---------------- bf16 MFMA GEMM: C = A * B^T (fp32 out) ----------------
// A: M x K bf16 row-major, B: N x K bf16 row-major. 128x128 tile, BK=64,
// global_load_lds(16B) with linear LDS + inverse-swizzled source; read-side
// XOR swizzle byte^=((row&7)<<4) -> conflict-free ds_read_b128 (T2, rule #21).
__global__ __launch_bounds__(256) void gemm_bf16(
    const unsigned short* __restrict__ A, const unsigned short* __restrict__ B,
    float* __restrict__ C, int M, int N, int K, long sA, long sB, long sC) {
  __shared__ unsigned short As[128 * 64];
  __shared__ unsigned short Bs[128 * 64];
  const int z = blockIdx.z;
  A += (long)z * sA;
  B += (long)z * sB;
  C += (long)z * sC;
  const int tid = threadIdx.x;
  const int wave = tid >> 6, lane = tid & 63;
  const int wr = wave >> 1, wc = wave & 1;
  const int tm0 = blockIdx.y * 128, tn0 = blockIdx.x * 128;
  f32x4 acc[4][4] = {};

  // staging source offsets: linear dest byte o -> row=o>>7, col=(o&127)^((row&7)<<4)
  int stRow[4], stCol[4];
#pragma unroll
  for (int t = 0; t < 4; ++t) {
    int o = t * 4096 + wave * 1024 + lane * 16;
    int row = o >> 7;
    stRow[t] = row;
    stCol[t] = ((o & 127) ^ ((row & 7) << 4)) >> 1;  // element offset within BK
  }

  for (int k0 = 0; k0 < K; k0 += 64) {
#pragma unroll
    for (int t = 0; t < 4; ++t) {
      const unsigned short* srcA = A + (long)(tm0 + stRow[t]) * K + k0 + stCol[t];
      __builtin_amdgcn_global_load_lds(
          (const __attribute__((address_space(1))) void*)srcA,
          (__attribute__((address_space(3))) void*)((char*)As + t * 4096 + wave * 1024),
          16, 0, 0);
    }
#pragma unroll
    for (int t = 0; t < 4; ++t) {
      const unsigned short* srcB = B + (long)(tn0 + stRow[t]) * K + k0 + stCol[t];
      __builtin_amdgcn_global_load_lds(
          (const __attribute__((address_space(1))) void*)srcB,
          (__attribute__((address_space(3))) void*)((char*)Bs + t * 4096 + wave * 1024),
          16, 0, 0);
    }
    __syncthreads();
#pragma unroll
    for (int ks = 0; ks < 2; ++ks) {
      const int cbase = ks * 64 + ((lane >> 4) << 4);
      bf16x8 av[4], bv[4];
#pragma unroll
      for (int m = 0; m < 4; ++m) {
        int row = wr * 64 + m * 16 + (lane & 15);
        av[m] = *(const bf16x8*)((const char*)As + row * 128 + (cbase ^ ((row & 7) << 4)));
      }
#pragma unroll
      for (int n = 0; n < 4; ++n) {
        int row = wc * 64 + n * 16 + (lane & 15);
        bv[n] = *(const bf16x8*)((const char*)Bs + row * 128 + (cbase ^ ((row & 7) << 4)));
      }
#pragma unroll
      for (int m = 0; m < 4; ++m)
#pragma unroll
        for (int n = 0; n < 4; ++n)
          acc[m][n] = __builtin_amdgcn_mfma_f32_16x16x32_bf16(av[m], bv[n], acc[m][n], 0, 0, 0);
    }
    __syncthreads();
  }
  // C/D layout: col=lane&15, row=(lane>>4)*4+j  (m89-verified)
#pragma unroll
  for (int m = 0; m < 4; ++m)
#pragma unroll
    for (int n = 0; n < 4; ++n)
#pragma unroll
      for (int j = 0; j < 4; ++j) {
        int row = tm0 + wr * 64 + m * 16 + ((lane >> 4) << 2) + j;
        int col = tn0 + wc * 64 + n * 16 + (lane & 15);
        C[(long)row * N + col] = acc[m][n][j];
      }
}

// ---------------- fused 3x3 patch box-sum (v+u passes) + inv-norm ----------------
__global__ void patchsum(const float* __restrict__ G, float* __restrict__ O0,
                         long sBuf, const float* __restrict__ invn, int batchBase) {
  int z = blockIdx.z;
  const float* I = G + (long)z * sBuf;
  float* O = O0 + (long)z * sBuf;
  int idx = blockIdx.x * 256 + threadIdx.x;
  int p = idx / LQ, q = idx - p * LQ;
  int i = p / WD, j = p % WD, li = q / WD, lj = q % WD;
  float s = 0.f;
#pragma unroll
  for (int du = -1; du <= 1; ++du) {
    if ((unsigned)(i + du) >= (unsigned)HD || (unsigned)(li + du) >= (unsigned)HD) continue;
#pragma unroll
    for (int dv = -1; dv <= 1; ++dv) {
      if ((unsigned)(j + dv) >= (unsigned)WD || (unsigned)(lj + dv) >= (unsigned)WD) continue;
      s += I[idx + (du * WD + dv) * (LQ + 1)];
    }
  }
  O[idx] = s * invn[(long)(batchBase + z) * LQ + q];
}

// ---------------- fused fuse_conv1 (flat) + fuse_conv2 (transposed flat) ----------------
__global__ void fusepass(const float* __restrict__ I0, float* __restrict__ O0, long sBuf) {
  int z = blockIdx.z;
  const float* I = I0 + (long)z * sBuf;
  float* O = O0 + (long)z * sBuf;
  int idx = blockIdx.x * 256 + threadIdx.x;
  int p = idx / LQ, l = idx - p * LQ;
  int i = p / WD, j = p % WD, li = l / WD, lj = l % WD;
  int pp = j * HD + i, ll = lj * HD + li;
  float s = 0.f;
#pragma unroll
  for (int d = -1; d <= 1; ++d) {
    int a = pp + d, bb = ll + d;
    if ((unsigned)a >= (unsigned)LQ || (unsigned)bb >= (unsigned)LQ) continue;
    int r = (a % HD) * WD + (a / HD);
    int c = (bb % HD) * WD + (bb / HD);
    long base = (long)r * LQ + c;
    float t = I[base];
    if (r > 0 && c > 0) t += I[base - (LQ + 1)];
    if (r < LQ - 1 && c < LQ - 1) t += I[base + (LQ + 1)];
    s += t;
  }
  O[idx] = s;
}

// ---------------- masked softmax over l per row p, argmax -> off, bf16 post out ----------------
__global__ __launch_bounds__(256) void softmax_row(const float* __restrict__ S, long sBuf,
                                                   const float* __restrict__ mmb,
                                                   unsigned short* __restrict__ Ab, long sAb,
                                                   float* __restrict__ offout, int batchBase) {
  int z = blockIdx.z;
  int b = batchBase + z;
  int p = blockIdx.x;
  const float* row = S + (long)z * sBuf + (long)p * LQ;
  unsigned short* arow = Ab + (long)z * sAb + (long)p * LQ;
  const float* mmr = mmb + (long)b * LQ;
  int tid = threadIdx.x;
  __shared__ float rbuf[256];
  __shared__ int ibuf[256];
  float zv[9], mloc[9];
  float mx = -1e30f;
#pragma unroll
  for (int it = 0; it < 9; ++it) {
    int l = it * 256 + tid;
    float m_ = mmr[l];
    float v = (m_ != 0.f) ? row[l] * 10.f : 0.f;
    zv[it] = v;
    mloc[it] = m_;
    mx = fmaxf(mx, v);
  }
  rbuf[tid] = mx;
  __syncthreads();
  for (int s = 128; s; s >>= 1) {
    if (tid < s) rbuf[tid] = fmaxf(rbuf[tid], rbuf[tid + s]);
    __syncthreads();
  }
  float M = rbuf[0];
  __syncthreads();
  float ev[9];
  float sum = 0.f;
#pragma unroll
  for (int it = 0; it < 9; ++it) {
    ev[it] = expf(zv[it] - M);
    sum += ev[it];
  }
  rbuf[tid] = sum;
  __syncthreads();
  for (int s = 128; s; s >>= 1) {
    if (tid < s) rbuf[tid] += rbuf[tid + s];
    __syncthreads();
  }
  float inv = 1.f / rbuf[0];
  __syncthreads();
  float bv = -1.f;
  int bi = 0;
#pragma unroll
  for (int it = 0; it < 9; ++it) {
    int l = it * 256 + tid;
    float post = (mloc[it] != 0.f) ? ev[it] * inv : 0.f;
    arow[l] = f2bf(post);
    if (post > bv) { bv = post; bi = l; }
  }
  rbuf[tid] = bv;
  ibuf[tid] = bi;
  __syncthreads();
  for (int s = 128; s; s >>= 1) {
    if (tid < s) {
      float ov = rbuf[tid + s];
      int oi = ibuf[tid + s];
      if (ov > rbuf[tid] || (ov == rbuf[tid] && oi < ibuf[tid])) {
        rbuf[tid] = ov;
        ibuf[tid] = oi;
      }
    }
    __syncthreads();
  }
  if (tid == 0) {
    int best = ibuf[0];
    int i = p / WD, j = p % WD;
    offout[((long)b * 2 + 0) * LQ + p] = (float)(best / WD - i);
    offout[((long)b * 2 + 1) * LQ + p] = (float)(best % WD - j);
  }
}

// ---------------- pack deconv weights WdT[(ku*4+kv)*64+o][l] as bf16 ----------------
__global__ void pack_wd(const float* __restrict__ bimg, unsigned short* __restrict__ WdT,
                        long sWd, int batchBase) {
  int z = blockIdx.z;
  int b = batchBase + z;
  int idx = blockIdx.x * 256 + threadIdx.x;      // < ND*LQ
  int n = idx / LQ, l = idx - n * LQ;
  int o = n % CC, kuv = n / CC, ku = kuv >> 2, kv = kuv & 3;
  int li = l / WD, lj = l % WD;
  int yy = 2 * li + ku - 1, xx = 2 * lj + kv - 1;
  float v = 0.f;
  if ((unsigned)yy < (unsigned)HH && (unsigned)xx < (unsigned)WW)
    v = bimg[((long)(b * CC + o) * HH + yy) * WW + xx];
  WdT[(long)z * sWd + idx] = f2bf(v);
}

// ---------------- scatter deconv GEMM result into HWC y_pre (incl. /4) ----------------
__global__ void scatter_deconv(const float* __restrict__ Mo, long sMo,
                               float* __restrict__ ypre, int batchBase) {
  int z = blockIdx.z;
  int b = batchBase + z;
  int o = threadIdx.x & 63, xq = threadIdx.x >> 6;
  int X = blockIdx.x * 4 + xq, Y = blockIdx.y;
  const float* M = Mo + (long)z * sMo;
  int iA, kuA, iB, kuB;
  if (Y & 1) { iA = (Y + 1) >> 1; kuA = 0; iB = (Y - 1) >> 1; kuB = 2; }
  else       { iA = Y >> 1;       kuA = 1; iB = (Y >> 1) - 1; kuB = 3; }
  int jA, kvA, jB, kvB;
  if (X & 1) { jA = (X + 1) >> 1; kvA = 0; jB = (X - 1) >> 1; kvB = 2; }
  else       { jA = X >> 1;       kvA = 1; jB = (X >> 1) - 1; kvB = 3; }
  int is[2] = {iA, iB}, kus[2] = {kuA, kuB};
  int js[2] = {jA, jB}, kvs[2] = {kvA, kvB};
  float s = 0.f;
#pragma unroll
  for (int a = 0; a < 2; ++a) {
    if ((unsigned)is[a] >= (unsigned)HD) continue;
#pragma unroll
    for (int c = 0; c < 2; ++c) {
      if ((unsigned)js[c] >= (unsigned)WD) continue;
      s += M[(long)(is[a] * WD + js[c]) * ND + (kus[a] * 4 + kvs[c]) * CC + o];
    }
  }
  ypre[((long)b * NPIX + Y * WW + X) * CC + o] = 0.25f * s;
}

// ---------------- pack conv weights as [oc][(u*3+v)*64+c] ----------------
__global__ void pack_w(const float* __restrict__ w1, const float* __restrict__ w2,
                       float* __restrict__ w1t, float* __restrict__ w2t) {
  int idx = blockIdx.x * 256 + threadIdx.x;      // < 2*CC*KC
  int sel = idx / (CC * KC);
  int r = idx % (CC * KC);
  int oc = r / KC, k = r % KC;
  int uv = k / CC, c = k % CC;
  const float* src = sel ? w2 : w1;
  float v = src[(long)(oc * CC + c) * 9 + uv];
  (sel ? w2t : w1t)[r] = v;
}

// ---------------- im2col from HWC source (3x3, pad 1), K order (u,v,c) ----------------
__global__ void im2col3(const float* __restrict__ src, float* __restrict__ Acol) {
  int t = blockIdx.x * 256 + threadIdx.x;        // one float4 per thread
  int m = t / 144, k4 = t % 144;
  int uv = k4 >> 4, c4 = k4 & 15;
  int u = uv / 3, v = uv % 3;
  int bl = m / NPIX, r = m % NPIX;
  int y = r / WW, x = r % WW;
  int yy = y + u - 1, xx = x + v - 1;
  float4 val = make_float4(0.f, 0.f, 0.f, 0.f);
  if ((unsigned)yy < (unsigned)HH && (unsigned)xx < (unsigned)WW)
    val = *(const float4*)(src + ((long)bl * NPIX + yy * WW + xx) * CC + c4 * 4);
  *(float4*)(Acol + (long)m * KC + k4 * 4) = val;
}

// ---------------- host ----------------
extern "C" void kernel_launch(void* const* d_in, const int* in_sizes, int n_in,
                              void* d_out, int out_size, void* d_ws, size_t ws_size,
                              hipStream_t stream) {
  const float* f = (const float*)d_in[0];
  const float* bimg = (const float*)d_in[1];
  const float* mask = (const float*)d_in[2];
  const float* w1 = (const float*)d_in[3];
  const float* b1 = (const float*)d_in[4];
  const float* w2 = (const float*)d_in[5];
  const float* b2 = (const float*)d_in[6];
  float* out = (float*)d_out;
  float* offout = out + 4L * CC * NPIX;          // off region (written as float)

  char* w = (char*)d_ws;
  float* fdt = (float*)w;  w += 4L * LQ * CC * 4;
  float* bdt = (float*)w;  w += 4L * LQ * CC * 4;
  float* sqb = (float*)w;  w += 4L * LQ * 4;
  float* invn = (float*)w; w += 4L * LQ * 4;
  float* mmb = (float*)w;  w += 4L * LQ * 4;
  float* w1t = (float*)w;  w += (long)CC * KC * 4;
  float* w2t = (float*)w;  w += (long)CC * KC * 4;
  float* ypre = (float*)w; w += 4L * NPIX * CC * 4;

  size_t fixed = (size_t)(w - (char*)d_ws);
  size_t szS_full = (size_t)4 * LL * 4;
  size_t szS_seq = (size_t)LL * 4;
  size_t szM_full = (size_t)4 * LQ * ND * 4;
  size_t szM_seq = (size_t)LQ * ND * 4;
  size_t need_full = fixed + szM_full + 2 * szS_full;
  bool full = (ws_size >= need_full);

  float* RM = (float*)w;
  float* R2 = (float*)(w + (full ? szM_full : szM_seq));
  char*  R3c = w + (full ? szM_full + szS_full : szM_seq + szS_seq);
  float* R3 = (float*)R3c;
  // bf16 overlays inside R3's region (used between softmax and deconv GEMM)
  unsigned short* Abf = (unsigned short*)R3c;
  unsigned short* Wbf = (unsigned short*)(R3c + (full ? 4L * LL * 2 : LL * 2));

  long sS = full ? LL : 0;
  long sM = full ? (long)LQ * ND : 0;
  long sWd = full ? (long)ND * LQ : 0;
  long sAb = full ? LL : 0;
  long sFD = (long)LQ * CC;
  int NB = full ? 4 : 1;
  int nIter = full ? 1 : 4;

  pack_w<<<dim3(288), 256, 0, stream>>>(w1, w2, w1t, w2t);

  for (int itb = 0; itb < nIter; ++itb) {
    int bb = full ? 0 : itb;
    pack_fdbd<<<dim3(576, 1, NB), 256, 0, stream>>>(f, bimg, fdt, bdt, bb);
    sq_kernel<<<dim3(LQ, 1, NB), 64, 0, stream>>>(bdt, sqb, bb);
    prep_l<<<dim3(9, 1, NB), 256, 0, stream>>>(sqb, mask, invn, mmb, bb);
    // Gram matrix G = fdt * bdt^T  (K = 64, fp32 — argmax-sensitive path)
    gemm_abt<128, 128, 0, 8><<<dim3(LQ / 128, LQ / 128, NB), 256, 0, stream>>>(
        fdt + (long)bb * sFD, bdt + (long)bb * sFD, R2, LQ, LQ, CC, sFD, sFD, sS,
        nullptr, 0);
    // fused 3x3 patch box-sum + inv-norm, then fused double fuse_conv
    patchsum<<<dim3(20736, 1, NB), 256, 0, stream>>>(R2, R3, sS, invn, bb);
    fusepass<<<dim3(20736, 1, NB), 256, 0, stream>>>(R3, R2, sS);
    softmax_row<<<dim3(LQ, 1, NB), 256, 0, stream>>>(R2, sS, mmb, Abf, sAb, offout, bb);
    // deconv as bf16 MFMA GEMM: post (2304x2304) @ WdT^T (1024x2304)
    pack_wd<<<dim3(9216, 1, NB), 256, 0, stream>>>(bimg, Wbf, sWd, bb);
    gemm_bf16<<<dim3(ND / 128, LQ / 128, NB), 256, 0, stream>>>(
        Abf, Wbf, RM, LQ, ND, LQ, sAb, sWd, sM);
    scatter_deconv<<<dim3(24, 96, NB), 256, 0, stream>>>(RM, sM, ypre, bb);

    if (full) {
      im2col3<<<dim3(20736), 256, 0, stream>>>(ypre, R2);
      gemm_abt<128, 64, 1, 4><<<dim3(1, 4 * NPIX / 128, 1), 256, 0, stream>>>(
          R2, w1t, R3, 4 * NPIX, CC, KC, 0, 0, 0, b1, 0);
      im2col3<<<dim3(20736), 256, 0, stream>>>(R3, R2);
      gemm_abt<128, 64, 2, 4><<<dim3(1, 4 * NPIX / 128, 1), 256, 0, stream>>>(
          R2, w2t, out, 4 * NPIX, CC, KC, 0, 0, 0, b2, 0);
    } else {
      im2col3<<<dim3(5184), 256, 0, stream>>>(ypre + (long)bb * NPIX * CC, R2);
      gemm_abt<128, 64, 1, 4><<<dim3(1, NPIX / 128, 1), 256, 0, stream>>>(
          R2, w1t, R3, NPIX, CC, KC, 0, 0, 0, b1, 0);
      im2col3<<<dim3(5184), 256, 0, stream>>>(R3, R2);
      gemm_abt<128, 64, 2, 4><<<dim3(1, NPIX / 128, 1), 256, 0, stream>>>(
          R2, w2t, out, NPIX, CC, KC, 0, 0, 0, b2, bb);
    }
  }
}